// Round 1
// baseline (107.226 us; speedup 1.0000x reference)
//
#include <hip/hip_runtime.h>
#include <math.h>

#define NG    2048
#define IMG_W 128
#define IMG_H 128
#define NPIX  (IMG_W * IMG_H)
#define NSEG  8
#define SEG   (NG / NSEG)      // 256
#define GSTRIDE 12             // floats per gaussian record (9 used + 3 pad, 48B)
#define F_FX  100.0f
#define F_FY  100.0f
#define NEARZ 1.1f
#define EPS_C 1e-6f

// ws layout (floats):
//   [0, NG*GSTRIDE)                      : sorted gaussian records (AoS)
//   [NG*GSTRIDE, NG*GSTRIDE + 4*NSEG*NPIX): segment partials (cr, cg, cb, T)
#define OFF_PART (NG * GSTRIDE)

__device__ __forceinline__ void quat_to_rot(float w, float x, float y, float z,
                                            float R[9]) {
    float n = sqrtf(w * w + x * x + y * y + z * z) + 1e-12f;
    w /= n; x /= n; y /= n; z /= n;
    R[0] = 1.0f - 2.0f * (y * y + z * z);
    R[1] = 2.0f * (x * y - w * z);
    R[2] = 2.0f * (x * z + w * y);
    R[3] = 2.0f * (x * y + w * z);
    R[4] = 1.0f - 2.0f * (x * x + z * z);
    R[5] = 2.0f * (y * z - w * x);
    R[6] = 2.0f * (x * z + w * y) * 0.0f; // placeholder (overwritten below)
    R[6] = 2.0f * (x * z - w * y);
    R[7] = 2.0f * (y * z + w * x);
    R[8] = 1.0f - 2.0f * (x * x + y * y);
}

// One block, 1024 threads: preprocess 2048 gaussians (2/thread, held in regs),
// bitonic-sort (depth,idx) keys in LDS, scatter sorted AoS records to ws.
__global__ __launch_bounds__(1024) void prep_sort_kernel(
    const float* __restrict__ pos, const float* __restrict__ rgb,
    const float* __restrict__ opa, const float* __restrict__ quat,
    const float* __restrict__ scale, const float* __restrict__ wq,
    const float* __restrict__ wt, float* __restrict__ ws) {
    __shared__ unsigned long long keys[NG];        // 16 KB
    __shared__ unsigned short pos_of[NG];          // 4 KB

    // camera rotation (every thread, cheap & uniform)
    float cm[9];
    quat_to_rot(wq[0], wq[1], wq[2], wq[3], cm);
    const float t0 = wt[0], t1 = wt[1], t2 = wt[2];

    float vu[2], vv[2], vA[2], vB[2], vC[2], vo[2], vr[2], vg[2], vb[2];

#pragma unroll
    for (int it = 0; it < 2; ++it) {
        const int i = threadIdx.x + it * 1024;
        const float px = pos[3 * i], py = pos[3 * i + 1], pz = pos[3 * i + 2];
        const float x = cm[0] * px + cm[1] * py + cm[2] * pz + t0;
        const float y = cm[3] * px + cm[4] * py + cm[5] * pz + t1;
        const float z = cm[6] * px + cm[7] * py + cm[8] * pz + t2;
        const float dn = sqrtf(x * x + y * y + z * z);
        bool mask = z > NEARZ;
        const float zs = mask ? z : 1.0f;
        const float u = x / zs;
        const float v = y / zs;
        mask = mask && (fabsf(u) < (IMG_W / (2.0f * F_FX))) &&
               (fabsf(v) < (IMG_H / (2.0f * F_FY)));
        const float iz = 1.0f / zs;
        const float iz2 = iz * iz;
        const float inrm = 1.0f / fmaxf(dn, 1e-8f);
        (void)inrm; // third J row never reaches the 2x2 cov block

        float Rg[9];
        quat_to_rot(quat[4 * i], quat[4 * i + 1], quat[4 * i + 2],
                    quat[4 * i + 3], Rg);
        const float s0 = scale[3 * i], s1 = scale[3 * i + 1],
                    s2 = scale[3 * i + 2];
        // RS[r][c] = Rg[r][c] * s_c
        const float RS0 = Rg[0] * s0, RS1 = Rg[1] * s1, RS2 = Rg[2] * s2;
        const float RS3 = Rg[3] * s0, RS4 = Rg[4] * s1, RS5 = Rg[5] * s2;
        const float RS6 = Rg[6] * s0, RS7 = Rg[7] * s1, RS8 = Rg[8] * s2;

        // JW rows 0,1  (JW = J @ rot)
        const float xiz2 = x * iz2, yiz2 = y * iz2;
        const float w00 = iz * cm[0] - xiz2 * cm[6];
        const float w01 = iz * cm[1] - xiz2 * cm[7];
        const float w02 = iz * cm[2] - xiz2 * cm[8];
        const float w10 = iz * cm[3] - yiz2 * cm[6];
        const float w11 = iz * cm[4] - yiz2 * cm[7];
        const float w12 = iz * cm[5] - yiz2 * cm[8];

        // e = JW_row · RS  (then cov2d = e·e)
        const float e00 = w00 * RS0 + w01 * RS3 + w02 * RS6;
        const float e01 = w00 * RS1 + w01 * RS4 + w02 * RS7;
        const float e02 = w00 * RS2 + w01 * RS5 + w02 * RS8;
        const float e10 = w10 * RS0 + w11 * RS3 + w12 * RS6;
        const float e11 = w10 * RS1 + w11 * RS4 + w12 * RS7;
        const float e12 = w10 * RS2 + w11 * RS5 + w12 * RS8;

        const float a = e00 * e00 + e01 * e01 + e02 * e02 + EPS_C;
        const float b = e00 * e10 + e01 * e11 + e02 * e12;
        const float c = e10 * e10 + e11 * e11 + e12 * e12 + EPS_C;
        const float invdet = 1.0f / fmaxf(a * c - b * b, 1e-12f);

        vu[it] = u;
        vv[it] = v;
        vA[it] = c * invdet;
        vB[it] = b * invdet;
        vC[it] = a * invdet;
        vo[it] = mask ? opa[i] : 0.0f;   // premultiplied mask (m in {0,1})
        vr[it] = rgb[3 * i];
        vg[it] = rgb[3 * i + 1];
        vb[it] = rgb[3 * i + 2];

        const float depth = mask ? dn : __int_as_float(0x7f800000);
        keys[i] = (((unsigned long long)__float_as_uint(depth)) << 32) |
                  (unsigned long long)(unsigned)i;
    }
    __syncthreads();

    // bitonic sort, ascending (keys unique -> equivalent to stable argsort)
    for (unsigned k = 2; k <= NG; k <<= 1) {
        for (unsigned j = k >> 1; j > 0; j >>= 1) {
            const unsigned t = threadIdx.x;
            const unsigned i = ((t & ~(j - 1)) << 1) | (t & (j - 1));
            const unsigned p = i | j;
            const unsigned long long ki = keys[i], kp = keys[p];
            const bool up = ((i & k) == 0);
            if ((ki > kp) == up) {
                keys[i] = kp;
                keys[p] = ki;
            }
            __syncthreads();
        }
    }

    // inverse permutation: pos_of[orig_idx] = sorted_position
#pragma unroll
    for (int it = 0; it < 2; ++it) {
        const int p = threadIdx.x + it * 1024;
        pos_of[(unsigned)(keys[p] & 0xffffffffULL)] = (unsigned short)p;
    }
    __syncthreads();

    // scatter register-held records into sorted AoS
#pragma unroll
    for (int it = 0; it < 2; ++it) {
        const int i = threadIdx.x + it * 1024;
        float* dst = ws + (int)pos_of[i] * GSTRIDE;
        dst[0] = vu[it];
        dst[1] = vv[it];
        dst[2] = vA[it];
        dst[3] = vB[it];
        dst[4] = vC[it];
        dst[5] = vo[it];
        dst[6] = vr[it];
        dst[7] = vg[it];
        dst[8] = vb[it];
        dst[9] = 0.0f; dst[10] = 0.0f; dst[11] = 0.0f;
    }
}

// grid (64 pixel-blocks, NSEG segments), 256 threads = 1 pixel/thread.
// Each block composites its 256-gaussian segment for 256 pixels and writes
// per-segment partial (premultiplied rgb, transmittance).
__global__ __launch_bounds__(256) void render_kernel(
    const float* __restrict__ ws, float* __restrict__ part) {
    __shared__ float gsh[SEG * GSTRIDE];  // 12 KB

    const int t = threadIdx.x;
    const int seg = blockIdx.y;
    const float* gsrc = ws + seg * SEG * GSTRIDE;

    // cooperative coalesced stage: 3072 floats = 768 float4
#pragma unroll
    for (int k = 0; k < (SEG * GSTRIDE) / (256 * 4); ++k) {
        const int idx = (k * 256 + t) * 4;
        *(float4*)(gsh + idx) = *(const float4*)(gsrc + idx);
    }
    __syncthreads();

    const int p = blockIdx.x * 256 + t;
    const int ix = p & (IMG_W - 1);
    const int iy = p >> 7;
    const float pu = (ix + 0.5f - IMG_W * 0.5f) / F_FX;
    const float pv = (iy + 0.5f - IMG_H * 0.5f) / F_FY;

    float T = 1.0f, cr = 0.0f, cg = 0.0f, cb = 0.0f;
#pragma unroll 4
    for (int j = 0; j < SEG; ++j) {
        const float4 q0 = *(const float4*)(gsh + j * GSTRIDE);      // u v A B
        const float4 q1 = *(const float4*)(gsh + j * GSTRIDE + 4);  // C o r g
        const float qb = gsh[j * GSTRIDE + 8];                      // b
        const float dx = pu - q0.x;
        const float dy = pv - q0.y;
        float pw = -0.5f * (q0.z * dx * dx + q1.x * dy * dy) + q0.w * dx * dy;
        pw = fminf(pw, 0.0f);
        const float al = fminf(q1.y * __expf(pw), 0.99f);
        const float wgt = T * al;
        cr += wgt * q1.z;
        cg += wgt * q1.w;
        cb += wgt * qb;
        T *= 1.0f - al;
    }

    const int o = seg * NPIX + p;
    part[o] = cr;
    part[NSEG * NPIX + o] = cg;
    part[2 * NSEG * NPIX + o] = cb;
    part[3 * NSEG * NPIX + o] = T;
}

// Combine segment partials in depth order (over-operator associativity).
__global__ __launch_bounds__(256) void combine_kernel(
    const float* __restrict__ part, float* __restrict__ out) {
    const int p = blockIdx.x * 256 + threadIdx.x;
    float T = 1.0f, cr = 0.0f, cg = 0.0f, cb = 0.0f;
#pragma unroll
    for (int s = 0; s < NSEG; ++s) {
        const int o = s * NPIX + p;
        cr += T * part[o];
        cg += T * part[NSEG * NPIX + o];
        cb += T * part[2 * NSEG * NPIX + o];
        T *= part[3 * NSEG * NPIX + o];
    }
    out[3 * p + 0] = cr;
    out[3 * p + 1] = cg;
    out[3 * p + 2] = cb;
}

extern "C" void kernel_launch(void* const* d_in, const int* in_sizes, int n_in,
                              void* d_out, int out_size, void* d_ws,
                              size_t ws_size, hipStream_t stream) {
    const float* pos   = (const float*)d_in[0];
    const float* rgb   = (const float*)d_in[1];
    const float* opa   = (const float*)d_in[2];
    const float* quat  = (const float*)d_in[3];
    const float* scale = (const float*)d_in[4];
    const float* wq    = (const float*)d_in[5];
    const float* wt    = (const float*)d_in[6];
    float* ws   = (float*)d_ws;
    float* part = ws + OFF_PART;
    float* out  = (float*)d_out;

    prep_sort_kernel<<<1, 1024, 0, stream>>>(pos, rgb, opa, quat, scale, wq,
                                             wt, ws);
    render_kernel<<<dim3(NPIX / 256, NSEG), 256, 0, stream>>>(ws, part);
    combine_kernel<<<NPIX / 256, 256, 0, stream>>>(part, out);
}